// Round 10
// baseline (136.832 us; speedup 1.0000x reference)
//
#include <hip/hip_runtime.h>
#include <hip/hip_bf16.h>
#include <math.h>

// Problem constants
#define BATCH   2048
#define TWO_B   4096
#define DIM     1024
#define NBLK2   1024          // 32x32 grid of 128x128 tiles
// 1 / (0.07 * ln(2)) : exp(s/T) = exp2(s * INV_T_LOG2E)
#define INV_T_LOG2E 20.60991907f
#define INV_T       14.285714285714286f

typedef float f32x4 __attribute__((ext_vector_type(4)));
typedef long  i64x2 __attribute__((ext_vector_type(2)));

// ---------------------------------------------------------------------------
// Kernel 1: L2-normalize 4096 rows -> fp8 e4m3 z[4096][1024] (4 MB).
// Wave-per-row; zero-inits rowsum + completion counter. No fences.
// ---------------------------------------------------------------------------
__global__ __launch_bounds__(256) void normalize_kernel(
        const float* __restrict__ feat, char* __restrict__ z,
        float* __restrict__ rowsum, unsigned int* __restrict__ counter) {
    const int lane = threadIdx.x & 63;
    const int row  = blockIdx.x * 4 + (threadIdx.x >> 6);
    if (lane == 0) rowsum[row] = 0.0f;
    if (blockIdx.x == 0 && threadIdx.x == 0) *counter = 0u;

    const float* src = feat + (row < BATCH ? (size_t)row * (2 * DIM)
                                           : (size_t)(row - BATCH) * (2 * DIM) + DIM);
    float4 v[4];
    float ss = 0.0f;
    #pragma unroll
    for (int t = 0; t < 4; ++t) {
        v[t] = ((const float4*)src)[t * 64 + lane];
        ss += v[t].x * v[t].x + v[t].y * v[t].y + v[t].z * v[t].z + v[t].w * v[t].w;
    }
    #pragma unroll
    for (int off = 32; off; off >>= 1) ss += __shfl_xor(ss, off, 64);
    const float scale = 1.0f / fmaxf(sqrtf(ss), 1e-12f);
    int4 o;
    int* op = (int*)&o;
    #pragma unroll
    for (int t = 0; t < 4; ++t) {
        int lo = __builtin_amdgcn_cvt_pk_fp8_f32(v[t].x * scale, v[t].y * scale, 0, false);
        op[t]  = __builtin_amdgcn_cvt_pk_fp8_f32(v[t].z * scale, v[t].w * scale, lo, true);
    }
    ((int4*)(z + (size_t)row * DIM))[lane] = o;   // 64 lanes x 16 B = one row
}

// ---------------------------------------------------------------------------
// Kernel 2: full sim = z z^T in fp8 e4m3. R10: NO LDS STAGING, NO MID-LOOP
// BARRIERS. Each lane loads its MFMA fragments straight from global (L1/L2)
// into registers: one dwordx4 covers rows (i*16+mn) x 64 contiguous bytes of
// K, split into two 8-B halves = two MFMA k-steps (identical K-permutation
// for A and B -> dot product invariant). Register double-buffer software
// pipeline: compiler inserts fine-grained vmcnt(8) (no barrier = no vmcnt(0)
// drain, the R5/R7/R9-proven dead end). Traffic 1 GB, L2-resident via the
// XCD-aware block swizzle (R8: FETCH 16.5->10.4 MB).
// Epilogue: LDS-transpose (20 KB scratch) + one coalesced 64-lane atomicAdd
// per wave; fence-free last-block finalize (R7/R8, proven).
// ---------------------------------------------------------------------------
__global__ __launch_bounds__(256) void gemm_fused(
        const char* __restrict__ z,
        float* __restrict__ rowsum,
        float* __restrict__ positives,
        unsigned int* __restrict__ counter,
        float* __restrict__ out) {
    __shared__ float ep_s[4][64 * 20];   // 20 KB epilogue scratch (per-wave)

    // XCD-aware swizzle: id&7 = round-robin XCD; 8x16 block region per XCD
    const int bid = blockIdx.x;
    const int xcd = bid & 7;
    const int t8  = bid >> 3;                   // 0..127 within region
    const int by  = (xcd >> 1) * 8 + (t8 & 7);
    const int bx  = (xcd & 1) * 16 + (t8 >> 3);
    const int rb  = by * 128;
    const int cb  = bx * 128;

    const int tid  = threadIdx.x;
    const int lane = tid & 63;
    const int wv   = tid >> 6;       // wave 0..3
    const int wr   = wv >> 1;        // wave row (0..1) -> 64-row subtile
    const int wc   = wv & 1;         // wave col (0..1) -> 64-col subtile
    const int q    = lane >> 4;      // quad 0..3 (16-B K-segment)
    const int mn   = lane & 15;

    f32x4 acc[4][4] = {};

    // Per-lane fragment pointers: row (tilebase + i*16 + mn), K-seg q.
    // One dwordx4 per (i, K-tile): 16 B = MFMA k-steps {2t, 2t+1}.
    const char* ap[4];
    const char* bp[4];
    #pragma unroll
    for (int i = 0; i < 4; ++i) {
        ap[i] = z + (size_t)(rb + wr * 64 + i * 16 + mn) * DIM + q * 16;
        bp[i] = z + (size_t)(cb + wc * 64 + i * 16 + mn) * DIM + q * 16;
    }

    i64x2 A0[4], B0[4], A1[4], B1[4];
    #pragma unroll
    for (int i = 0; i < 4; ++i) {
        A0[i] = *(const i64x2*)(ap[i]);
        B0[i] = *(const i64x2*)(bp[i]);
    }

    #pragma unroll
    for (int t = 0; t < 16; t += 2) {
        // prefetch K-tile t+1 into set 1 (8 loads in flight over set-0 MFMAs)
        const int k1 = (t + 1) * 64;
        #pragma unroll
        for (int i = 0; i < 4; ++i) {
            A1[i] = *(const i64x2*)(ap[i] + k1);
            B1[i] = *(const i64x2*)(bp[i] + k1);
        }
        // compute on set 0 (K-tile t)
        #pragma unroll
        for (int i = 0; i < 4; ++i)
            #pragma unroll
            for (int j = 0; j < 4; ++j) {
                acc[i][j] = __builtin_amdgcn_mfma_f32_16x16x32_fp8_fp8(
                                A0[i].x, B0[j].x, acc[i][j], 0, 0, 0);
                acc[i][j] = __builtin_amdgcn_mfma_f32_16x16x32_fp8_fp8(
                                A0[i].y, B0[j].y, acc[i][j], 0, 0, 0);
            }
        // prefetch K-tile t+2 into set 0
        if (t + 2 < 16) {
            const int k2 = (t + 2) * 64;
            #pragma unroll
            for (int i = 0; i < 4; ++i) {
                A0[i] = *(const i64x2*)(ap[i] + k2);
                B0[i] = *(const i64x2*)(bp[i] + k2);
            }
        }
        // compute on set 1 (K-tile t+1)
        #pragma unroll
        for (int i = 0; i < 4; ++i)
            #pragma unroll
            for (int j = 0; j < 4; ++j) {
                acc[i][j] = __builtin_amdgcn_mfma_f32_16x16x32_fp8_fp8(
                                A1[i].x, B1[j].x, acc[i][j], 0, 0, 0);
                acc[i][j] = __builtin_amdgcn_mfma_f32_16x16x32_fp8_fp8(
                                A1[i].y, B1[j].y, acc[i][j], 0, 0, 0);
            }
    }

    // ---- Epilogue (C/D layout col = lane&15, row = (lane>>4)*4 + reg) ----
    float* ep = ep_s[wv];
    #pragma unroll
    for (int i = 0; i < 4; ++i) {
        #pragma unroll
        for (int reg = 0; reg < 4; ++reg) {
            const int r  = rb + wr * 64 + i * 16 + q * 4 + reg;
            const int pc = (r + BATCH) & (TWO_B - 1);
            float local = 0.0f;
            #pragma unroll
            for (int j = 0; j < 4; ++j) {
                const int c = cb + wc * 64 + j * 16 + mn;
                const float s = acc[i][j][reg];
                if (c == pc)   // unique writer per r
                    __hip_atomic_store(&positives[r], s, __ATOMIC_RELAXED,
                                       __HIP_MEMORY_SCOPE_AGENT);
                local += (c == r) ? 0.0f : exp2f(s * INV_T_LOG2E);
            }
            ep[(i * 16 + q * 4 + reg) * 20 + mn] = local;
        }
    }
    // wave-private read-back; one coalesced 64-lane atomic per wave
    {
        const float4 p0 = *(const float4*)&ep[lane * 20 + 0];
        const float4 p1 = *(const float4*)&ep[lane * 20 + 4];
        const float4 p2 = *(const float4*)&ep[lane * 20 + 8];
        const float4 p3 = *(const float4*)&ep[lane * 20 + 12];
        const float tot = (p0.x + p0.y + p0.z + p0.w) + (p1.x + p1.y + p1.z + p1.w)
                        + (p2.x + p2.y + p2.z + p2.w) + (p3.x + p3.y + p3.z + p3.w);
        atomicAdd(&rowsum[rb + wr * 64 + lane], tot);
    }

    // ---- fence-free last-block finalize (R7/R8, proven) ----
    __shared__ int amLast;
    __syncthreads();
    if (tid == 0) {
        unsigned int old = __hip_atomic_fetch_add(counter, 1u, __ATOMIC_RELAXED,
                                                  __HIP_MEMORY_SCOPE_AGENT);
        amLast = (old == NBLK2 - 1);
    }
    __syncthreads();
    if (amLast) {
        float acc2 = 0.0f;
        for (int r = tid; r < TWO_B; r += 256) {
            float rs = __hip_atomic_load(&rowsum[r], __ATOMIC_RELAXED,
                                         __HIP_MEMORY_SCOPE_AGENT);
            float p  = __hip_atomic_load(&positives[r], __ATOMIC_RELAXED,
                                         __HIP_MEMORY_SCOPE_AGENT);
            acc2 += logf(rs) - p * INV_T;
        }
        #pragma unroll
        for (int off = 32; off; off >>= 1) acc2 += __shfl_down(acc2, off, 64);
        __shared__ float s_part[4];
        if ((tid & 63) == 0) s_part[tid >> 6] = acc2;
        __syncthreads();
        if (tid == 0)
            out[0] = (s_part[0] + s_part[1] + s_part[2] + s_part[3]) * (1.0f / TWO_B);
    }
}

extern "C" void kernel_launch(void* const* d_in, const int* in_sizes, int n_in,
                              void* d_out, int out_size, void* d_ws, size_t ws_size,
                              hipStream_t stream) {
    const float* feat = (const float*)d_in[0];
    char* ws = (char*)d_ws;

    // workspace: z fp8[4096][1024] (4 MB) | rowsum f32[4096] | positives f32[4096] | counter
    char* zq              = ws;
    float* rowsum         = (float*)(ws + (size_t)TWO_B * DIM);
    float* positives      = rowsum + TWO_B;
    unsigned int* counter = (unsigned int*)(positives + TWO_B);
    float* out            = (float*)d_out;

    normalize_kernel<<<TWO_B / 4, 256, 0, stream>>>(feat, zq, rowsum, counter);
    gemm_fused<<<NBLK2, 256, 0, stream>>>(zq, rowsum, positives, counter, out);
}